// Round 10
// baseline (1592.547 us; speedup 1.0000x reference)
//
#include <hip/hip_runtime.h>
#include <hip/hip_bf16.h>
#include <cstdint>
#include <cmath>

// Self-attention, B=8 T=1024 H=8 D=512 (hidden 4096), fp32 in/out, bf16 MFMA compute.
// Flash-fused attention (QK^T -> online softmax -> PV in one kernel; S never in memory),
// group-adaptive over batches: g in {8,4,2}, R(g) = 92,274,688 + g*25,165,824 bytes;
// g=2 footprint == 142,606,336 B (byte-identical to the proven round-2 layout).
// Projections / out-proj on the 256x256/BK=64 gemm256 (R7/R8, verified).

typedef __attribute__((ext_vector_type(8))) short short8;
typedef __attribute__((ext_vector_type(4))) float f32x4;

#define DEVINL __device__ __forceinline__

DEVINL float bf2f(ushort u) { union { uint32_t i; float f; } w; w.i = (uint32_t)u << 16; return w.f; }
DEVINL ushort f2bf(float f) {
  union { float f; uint32_t i; } w; w.f = f;
  uint32_t r = w.i + 0x7FFFu + ((w.i >> 16) & 1u);   // RNE
  return (ushort)(r >> 16);
}

DEVINL void gl_lds16(const ushort* g, ushort* l) {
  __builtin_amdgcn_global_load_lds(
      (const __attribute__((address_space(1))) uint32_t*)g,
      (__attribute__((address_space(3))) uint32_t*)l, 16, 0, 0);
}

// ---------------- fp32 -> bf16 convert (8 elems/thread), optional scale ----------------
__global__ __launch_bounds__(256) void cvt_f32_bf16(const float* __restrict__ in,
                                                    ushort* __restrict__ out,
                                                    int n8, float scale) {
  int i = blockIdx.x * 256 + threadIdx.x;
  if (i >= n8) return;
  const float4* p = (const float4*)in + (size_t)i * 2;
  float4 a = p[0], b = p[1];
  short8 o;
  o[0] = (short)f2bf(a.x * scale); o[1] = (short)f2bf(a.y * scale);
  o[2] = (short)f2bf(a.z * scale); o[3] = (short)f2bf(a.w * scale);
  o[4] = (short)f2bf(b.x * scale); o[5] = (short)f2bf(b.y * scale);
  o[6] = (short)f2bf(b.z * scale); o[7] = (short)f2bf(b.w * scale);
  ((short8*)out)[i] = o;
}

// ---------------- zero fp32 buffer ----------------
__global__ __launch_bounds__(256) void zerof4(float4* __restrict__ p, int n4) {
  int i = blockIdx.x * 256 + threadIdx.x;
  if (i < n4) p[i] = float4{0.f, 0.f, 0.f, 0.f};
}

// ================= 256x256 / BK=64 / 8-wave bf16 C = A * B^T (verified R7/R8) =================
template<bool CSKIP, bool CKB, int EPI, bool ZBH, bool SWZ>
__global__ __launch_bounds__(512, 2) void gemm256(
    const ushort* __restrict__ A0, long long sAb, long long sAh,
    const ushort* __restrict__ B0, long long sBb, long long sBh,
    void* __restrict__ C0, long long sCb, long long sCh,
    int lda, int ldb, int ldc, int K)
{
  int bm, bn;
  if (SWZ) {
    const int X = gridDim.x, nwg = X * gridDim.y;
    const int bid = blockIdx.y * X + blockIdx.x;
    const int cpx = nwg >> 3;
    const int swz = (bid & 7) * cpx + (bid >> 3);
    bm = swz % X; bn = swz / X;
  } else {
    bm = blockIdx.x; bn = blockIdx.y;
  }
  const int bz = blockIdx.z;
  if (CSKIP && bn > bm) return;
  long long za, zb, zc;
  if (ZBH) {
    const long long bi = bz >> 3, hi = bz & 7;
    za = bi * sAb + hi * sAh; zb = bi * sBb + hi * sBh; zc = bi * sCb + hi * sCh;
  } else {
    za = (long long)bz * sAh; zb = (long long)bz * sBh; zc = (long long)bz * sCh;
  }
  const ushort* A = A0 + za;
  const ushort* B = B0 + zb;
  int kend = K;
  if (CKB) { int kb = (bm + 1) * 256; kend = kb < K ? kb : K; }

  __shared__ ushort smem[65536];

  const int tid = threadIdx.x;
  const int wid = tid >> 6, lane = tid & 63;
  const int wr = wid >> 2, wc = wid & 3;
  const int l15 = lane & 15, kq = lane >> 4;

  const int srow8 = lane >> 3;
  const int schunk = ((lane & 7) ^ srow8) * 8;
  const ushort* ag = A + (size_t)(bm * 256 + wid * 8 + srow8) * lda + schunk;
  const ushort* bg = B + (size_t)(bn * 256 + wid * 8 + srow8) * ldb + schunk;

  auto STA = [&](int buf, int band, int kk) {
    gl_lds16(ag + (size_t)band * 64 * lda + kk, &smem[buf * 32768 + band * 4096 + wid * 512]);
  };
  auto STB = [&](int buf, int band, int kk) {
    gl_lds16(bg + (size_t)band * 64 * ldb + kk, &smem[buf * 32768 + 16384 + band * 4096 + wid * 512]);
  };
  auto STAGE8 = [&](int buf, int kk) {
    STB(buf, 0, kk); STB(buf, 1, kk); STB(buf, 2, kk); STB(buf, 3, kk);
    STA(buf, 0, kk); STA(buf, 2, kk); STA(buf, 1, kk); STA(buf, 3, kk);
  };

  f32x4 acc[8][4] = {};
  const int nt = kend >> 6;

  STAGE8(0, 0);

  for (int t = 0; t < nt; ++t) {
    const int cur = t & 1;
    const ushort* As = &smem[cur * 32768];
    const ushort* Bs = As + 16384;
    const bool pre = (t + 1 < nt);

    short8 bq[4], av[4];
    auto LDB = [&](int ks) {
#pragma unroll
      for (int n = 0; n < 4; ++n)
        bq[n] = *(const short8*)
            &Bs[(wc * 64 + n * 16 + l15) * 64 + (((ks * 4 + kq) ^ (l15 & 7)) * 8)];
    };
    auto LDA = [&](int mh, int ks) {
#pragma unroll
      for (int m = 0; m < 4; ++m)
        av[m] = *(const short8*)
            &As[(wr * 128 + mh * 64 + m * 16 + l15) * 64 + (((ks * 4 + kq) ^ (l15 & 7)) * 8)];
    };
    auto MFMAQ = [&](int mh) {
      __builtin_amdgcn_s_setprio(1);
#pragma unroll
      for (int m = 0; m < 4; ++m)
#pragma unroll
        for (int n = 0; n < 4; ++n)
          acc[mh * 4 + m][n] =
              __builtin_amdgcn_mfma_f32_16x16x32_bf16(av[m], bq[n], acc[mh * 4 + m][n], 0, 0, 0);
      __builtin_amdgcn_s_setprio(0);
    };

    if (pre) {
      STAGE8(cur ^ 1, (t + 1) << 6);
      asm volatile("s_waitcnt vmcnt(10)" ::: "memory");
    } else {
      asm volatile("s_waitcnt vmcnt(2)" ::: "memory");
    }
    __builtin_amdgcn_sched_barrier(0);
    __builtin_amdgcn_s_barrier();
    __builtin_amdgcn_sched_barrier(0);
    LDB(0); LDA(0, 0); MFMAQ(0);

    if (pre) asm volatile("s_waitcnt vmcnt(8)" ::: "memory");
    else     asm volatile("s_waitcnt vmcnt(0)" ::: "memory");
    __builtin_amdgcn_sched_barrier(0);
    __builtin_amdgcn_s_barrier();
    __builtin_amdgcn_sched_barrier(0);
    LDA(1, 0); MFMAQ(1);

    LDB(1); LDA(0, 1); MFMAQ(0);

    LDA(1, 1); MFMAQ(1);
    asm volatile("s_waitcnt lgkmcnt(0)" ::: "memory");
    __builtin_amdgcn_sched_barrier(0);
    __builtin_amdgcn_s_barrier();
    __builtin_amdgcn_sched_barrier(0);
  }

  if constexpr (EPI == 0) {
#pragma unroll
    for (int m = 0; m < 8; ++m)
#pragma unroll
      for (int n = 0; n < 4; ++n)
#pragma unroll
        for (int r = 0; r < 4; ++r) {
          const int row = wr * 128 + m * 16 + kq * 4 + r;
          const int col = wc * 64 + n * 16 + l15;
          smem[row * 256 + (((col >> 3) ^ (row & 31)) * 8) + (col & 7)] = f2bf(acc[m][n][r]);
        }
    __syncthreads();
    ushort* C = (ushort*)C0 + zc;
#pragma unroll
    for (int j = 0; j < 16; ++j) {
      const int chi = j * 512 + tid;
      const int row = chi >> 5, cc = chi & 31;
      *(short8*)&C[(size_t)(bm * 256 + row) * ldc + bn * 256 + cc * 8] =
          *(const short8*)&smem[row * 256 + ((cc ^ (row & 31)) * 8)];
    }
  } else {
    float* C = (float*)C0 + zc;
#pragma unroll
    for (int m = 0; m < 8; ++m)
#pragma unroll
      for (int n = 0; n < 4; ++n)
#pragma unroll
        for (int r = 0; r < 4; ++r)
          atomicAdd(&C[(size_t)(bm * 256 + wr * 128 + m * 16 + kq * 4 + r) * ldc
                       + bn * 256 + wc * 64 + n * 16 + l15], acc[m][n][r]);
  }
}

// ================= fused flash attention (group-local) =================
// Grid (8 q-blocks, 8g bh), 512 thr / 8 waves; wave owns 16 q-rows (QBLK=128).
// QKg: [g*1024][8192] rows = group tokens, cols 0..4095 Q | 4096..8191 K (head h at h*512).
// Vtg: [8g][512][1024]. Output AOg: [g*1024][4096].
__global__ __launch_bounds__(512) void fused_attn(
    const ushort* __restrict__ QKg, const ushort* __restrict__ Vtg,
    ushort* __restrict__ AOg)
{
  const int qb = blockIdx.x;            // 0..7
  const int bh = blockIdx.y;            // 0..8g-1
  const int b = bh >> 3, h = bh & 7;    // group-local batch, head

  __shared__ ushort smem[69632];        // 2x(K 16384 | V 16384) + 8x512 P-scratch

  const int tid = threadIdx.x;
  const int wid = tid >> 6, lane = tid & 63;
  const int l15 = lane & 15, kq = lane >> 4;

  const ushort* Qb = QKg + (size_t)(b * 1024 + qb * 128 + wid * 16) * 8192 + h * 512;
  const ushort* Kb = QKg + (size_t)b * 1024 * 8192 + 4096 + h * 512;
  const ushort* Vb = Vtg + (size_t)bh * 524288;    // [512][1024]

  // Q fragments: lane l15 = row, cols kt*32 + kq*8
  short8 qf[16];
#pragma unroll
  for (int kt = 0; kt < 16; ++kt)
    qf[kt] = *(const short8*)&Qb[(size_t)l15 * 8192 + kt * 32 + kq * 8];

  // staging (rule #21): linear gl_lds dest + inverse-swizzled per-lane global source.
  // K rows r (1KB): LDS chunk p holds global chunk (p&56)|((p^r)&7).
  // V rows d (64B): LDS chunk c holds global chunk c^(d&3).
  auto STAGE = [&](int buf, int t) {
    const int s0 = t * 32;
#pragma unroll
    for (int q = 0; q < 4; ++q) {
      const int r = wid * 4 + q;
      const int sc = (lane & 56) | ((lane ^ r) & 7);
      gl_lds16(Kb + (size_t)(s0 + r) * 8192 + sc * 8, &smem[buf * 32768 + r * 512]);
    }
#pragma unroll
    for (int q = 0; q < 4; ++q) {
      const int dbase = wid * 64 + q * 16;
      const int d = dbase + (lane >> 2);
      const int sc = ((lane & 3) ^ ((lane >> 2) & 3)) * 8;
      gl_lds16(Vb + (size_t)d * 1024 + s0 + sc, &smem[buf * 32768 + 16384 + dbase * 32]);
    }
  };

  const int nkv = (qb + 1) * 4;
  const int qrow0 = qb * 128 + wid * 16 + kq * 4;   // + r
  float mrow[4] = {-3e38f, -3e38f, -3e38f, -3e38f};
  float lrow[4] = {0.f, 0.f, 0.f, 0.f};
  f32x4 accO[32] = {};
  ushort* PS = &smem[65536 + wid * 512];

  STAGE(0, 0);
  for (int t = 0; t < nkv; ++t) {
    const int cur = t & 1;
    if (t + 1 < nkv) {
      STAGE(cur ^ 1, t + 1);
      asm volatile("s_waitcnt vmcnt(8)" ::: "memory");
    } else {
      asm volatile("s_waitcnt vmcnt(0)" ::: "memory");
    }
    __builtin_amdgcn_sched_barrier(0);
    __builtin_amdgcn_s_barrier();
    __builtin_amdgcn_sched_barrier(0);

    const ushort* KL = &smem[cur * 32768];
    const ushort* VL = KL + 16384;
    const int s0 = t * 32;

    // ---- QK^T: S-tile 16q x 32s, Q from regs, K from LDS
    f32x4 sA = {0.f, 0.f, 0.f, 0.f}, sB = {0.f, 0.f, 0.f, 0.f};
    __builtin_amdgcn_s_setprio(1);
#pragma unroll
    for (int kt = 0; kt < 16; ++kt) {
      const int gc = kt * 4 + kq;
      const int pos = ((gc & 56) | ((gc ^ l15) & 7)) * 8;
      short8 k0 = *(const short8*)&KL[l15 * 512 + pos];
      short8 k1 = *(const short8*)&KL[(16 + l15) * 512 + pos];
      sA = __builtin_amdgcn_mfma_f32_16x16x32_bf16(qf[kt], k0, sA, 0, 0, 0);
      sB = __builtin_amdgcn_mfma_f32_16x16x32_bf16(qf[kt], k1, sB, 0, 0, 0);
    }
    __builtin_amdgcn_s_setprio(0);

    // ---- causal mask + online softmax (rows kq*4+r; cols s0+l15 / s0+16+l15)
    float p0[4], p1[4], rmax[4];
    int nogrow = 1;
#pragma unroll
    for (int r = 0; r < 4; ++r) {
      float a = sA[r], c = sB[r];
      if (s0 + l15      > qrow0 + r) a = -3e38f;
      if (s0 + 16 + l15 > qrow0 + r) c = -3e38f;
      p0[r] = a; p1[r] = c;
      float mx = fmaxf(a, c);
      mx = fmaxf(mx, __shfl_xor(mx, 1));
      mx = fmaxf(mx, __shfl_xor(mx, 2));
      mx = fmaxf(mx, __shfl_xor(mx, 4));
      mx = fmaxf(mx, __shfl_xor(mx, 8));
      rmax[r] = mx;
      nogrow = nogrow && (mx <= mrow[r]);
    }
    if (__all(nogrow)) {                       // exact skip: scale == 1
#pragma unroll
      for (int r = 0; r < 4; ++r) {
        p0[r] = __expf(p0[r] - mrow[r]);
        p1[r] = __expf(p1[r] - mrow[r]);
        float s = p0[r] + p1[r];
        s += __shfl_xor(s, 1); s += __shfl_xor(s, 2);
        s += __shfl_xor(s, 4); s += __shfl_xor(s, 8);
        lrow[r] += s;
      }
    } else {
#pragma unroll
      for (int r = 0; r < 4; ++r) {
        float mn = fmaxf(mrow[r], rmax[r]);
        float sc = __expf(mrow[r] - mn);
        mrow[r] = mn;
        p0[r] = __expf(p0[r] - mn);
        p1[r] = __expf(p1[r] - mn);
        float s = p0[r] + p1[r];
        s += __shfl_xor(s, 1); s += __shfl_xor(s, 2);
        s += __shfl_xor(s, 4); s += __shfl_xor(s, 8);
        lrow[r] = lrow[r] * sc + s;
#pragma unroll
        for (int j = 0; j < 32; ++j) accO[j][r] *= sc;
      }
    }

    // ---- P (16x32) -> bf16 A-frag via wave-private LDS transpose (XOR on q&3)
#pragma unroll
    for (int r = 0; r < 4; ++r) {
      const int q = kq * 4 + r;
      const int s1 = 16 + l15;
      PS[q * 32 + (((l15 >> 3) ^ (q & 3)) * 8) + (l15 & 7)] = f2bf(p0[r]);
      PS[q * 32 + (((s1 >> 3) ^ (q & 3)) * 8) + (s1 & 7)]   = f2bf(p1[r]);
    }
    short8 pa = *(const short8*)&PS[l15 * 32 + ((kq ^ (l15 & 3)) * 8)];

    // ---- PV: accO[j] (rows q, cols j*16+l15) += P · V
    __builtin_amdgcn_s_setprio(1);
#pragma unroll
    for (int j = 0; j < 32; ++j) {
      short8 bv = *(const short8*)&VL[(j * 16 + l15) * 32 + ((kq ^ (l15 & 3)) * 8)];
      accO[j] = __builtin_amdgcn_mfma_f32_16x16x32_bf16(pa, bv, accO[j], 0, 0, 0);
    }
    __builtin_amdgcn_s_setprio(0);

    asm volatile("s_waitcnt lgkmcnt(0)" ::: "memory");
    __builtin_amdgcn_sched_barrier(0);
    __builtin_amdgcn_s_barrier();                  // buf handoff; vmem prefetch survives
    __builtin_amdgcn_sched_barrier(0);
  }

  // ---- epilogue: O/l -> bf16, wave-private LDS stage (16x512 swizzled), coalesced stores
  float inv[4];
#pragma unroll
  for (int r = 0; r < 4; ++r) inv[r] = 1.f / lrow[r];
  ushort* OS = &smem[wid * 8192];
#pragma unroll
  for (int j = 0; j < 32; ++j)
#pragma unroll
    for (int r = 0; r < 4; ++r) {
      const int q = kq * 4 + r;
      const int col = j * 16 + l15;
      const int ch = col >> 3;
      OS[q * 512 + (((ch & 56) | ((ch ^ q) & 7)) * 8) + (col & 7)] = f2bf(accO[j][r] * inv[r]);
    }
  ushort* AOb = AOg + (size_t)(b * 1024 + qb * 128 + wid * 16) * 4096 + h * 512;
#pragma unroll
  for (int it = 0; it < 16; ++it) {
    const int q = it, c = lane;
    const int pos = (c & 56) | ((c ^ q) & 7);
    *(short8*)&AOb[(size_t)q * 4096 + c * 8] = *(const short8*)&OS[q * 512 + pos * 8];
  }
}

// ---------------- V transpose: Vtmp[b*1024+s][h*512+d] -> Vt[bh][d][s] (group-local) -------
__global__ __launch_bounds__(256) void transposeV(const ushort* __restrict__ Vtmp,
                                                  ushort* __restrict__ Vt) {
  __shared__ ushort tile[64][72];
  const int bx = blockIdx.x;          // s-tile (16)
  const int by = blockIdx.y;          // d-tile (8)
  const int bz = blockIdx.z;          // bh (8g)
  const int b = bz >> 3, h = bz & 7;
  const int t = threadIdx.x;
  const int r = t >> 2, c = (t & 3) * 16;

  const ushort* src = Vtmp + (size_t)(b * 1024 + bx * 64 + r) * 4096 + h * 512 + by * 64 + c;
  short8 v0 = *(const short8*)src;
  short8 v1 = *(const short8*)(src + 8);
#pragma unroll
  for (int j = 0; j < 8; ++j) { tile[r][c + j] = (ushort)v0[j]; tile[r][c + 8 + j] = (ushort)v1[j]; }
  __syncthreads();

  ushort* dst = Vt + (size_t)(bz * 512 + by * 64 + r) * 1024 + bx * 64 + c;
  short8 o0, o1;
#pragma unroll
  for (int j = 0; j < 8; ++j) { o0[j] = (short)tile[c + j][r]; o1[j] = (short)tile[c + 8 + j][r]; }
  *(short8*)dst = o0;
  *(short8*)(dst + 8) = o1;
}

// ---------------- launch ----------------
extern "C" void kernel_launch(void* const* d_in, const int* in_sizes, int n_in,
                              void* d_out, int out_size, void* d_ws, size_t ws_size,
                              hipStream_t stream) {
  const float* x  = (const float*)d_in[0];
  const float* Wq = (const float*)d_in[1];
  const float* Wk = (const float*)d_in[2];
  const float* Wv = (const float*)d_in[3];
  const float* Wo = (const float*)d_in[4];
  float* out = (float*)d_out;

  // group size: R(g) = 92,274,688 + g*25,165,824 bytes; g=2 == proven 142,606,336 floor.
  const int g = (ws_size >= 293601280ull) ? 8 : (ws_size >= 192937984ull) ? 4 : 2;
  const int ng = 8 / g;

  // workspace layout (ushort elements)
  ushort* xb   = (ushort*)d_ws;                 //  8192*512     = 4,194,304
  ushort* Wqkv = xb   + (size_t)4194304;        // 12288*512     = 6,291,456
  ushort* Wob  = Wqkv + (size_t)6291456;        //   512*4096    = 2,097,152
  ushort* AO   = Wob  + (size_t)2097152;        //  8192*4096    = 33,554,432
  ushort* QKg  = AO   + (size_t)33554432;       //  g*1024*8192  = g*8,388,608
  ushort* Vtg  = QKg  + (size_t)g * 8388608;    //  g*8*512*1024 = g*4,194,304

  const float iscale = (float)(1.0 / pow(512.0, 0.25));   // folded into Wq, Wk

  cvt_f32_bf16<<<2048, 256, 0, stream>>>(x,  xb,             524288, 1.0f);
  cvt_f32_bf16<<<1024, 256, 0, stream>>>(Wq, Wqkv,           262144, iscale);
  cvt_f32_bf16<<<1024, 256, 0, stream>>>(Wk, Wqkv + 2097152, 262144, iscale);
  cvt_f32_bf16<<<1024, 256, 0, stream>>>(Wv, Wqkv + 4194304, 262144, 1.0f);
  cvt_f32_bf16<<<1024, 256, 0, stream>>>(Wo, Wob,            262144, 1.0f);

  for (int grp = 0; grp < ng; ++grp) {
    const ushort* xg = xb + (size_t)grp * g * 524288;
    ushort* AOg = AO + (size_t)grp * g * 4194304;

    // QKg = x[grp] @ (Wq|Wk)^T : [g*1024 x 8192]
    gemm256<false, false, 0, false, true><<<dim3(g * 4, 32, 1), 512, 0, stream>>>(
        xg, 0, 0, Wqkv, 0, 0, QKg, 0, 0, 512, 512, 8192, 512);

    // V-tmp = x[grp] @ Wv^T : [g*1024 x 4096] -> AOg region
    gemm256<false, false, 0, false, true><<<dim3(g * 4, 16, 1), 512, 0, stream>>>(
        xg, 0, 0, Wqkv + 4194304, 0, 0, AOg, 0, 0, 512, 512, 4096, 512);

    // V transpose -> Vtg[bh][d][s]
    transposeV<<<dim3(16, 8, 8 * g), 256, 0, stream>>>(AOg, Vtg);

    // fused flash attention -> AOg (overwrites V-tmp, already consumed)
    fused_attn<<<dim3(8, 8 * g), 512, 0, stream>>>(QKg, Vtg, AOg);
  }

  // out = AO @ Wo^T, fp32, K split x4 with atomic accumulate
  zerof4<<<4096, 256, 0, stream>>>((float4*)out, 1048576);
  gemm256<false, false, 2, false, true><<<dim3(32, 2, 4), 512, 0, stream>>>(
      AO,  0, 1024LL,
      Wob, 0, 1024LL,
      out, 0, 0LL,
      4096, 4096, 512, 1024);
}

// Round 11
// 611.221 us; speedup vs baseline: 2.6055x; 2.6055x over previous
//
#include <hip/hip_runtime.h>
#include <hip/hip_bf16.h>
#include <cstdint>
#include <cmath>

// Self-attention, B=8 T=1024 H=8 D=512 (hidden 4096), fp32 in/out, bf16 MFMA compute.
// Flash-fused attention (QK^T -> online softmax -> PV in one kernel; S never in memory),
// group-adaptive over batches: g in {8,4,2}, R(g) = 92,274,688 + g*25,165,824 bytes.
// R11 fix: fused_attn __launch_bounds__(512,2) (spill fix — R10 allocated 128 VGPR and
// spilled the 128-f32 accumulator to scratch: 1.34 GB/dispatch extra HBM traffic);
// single-path online softmax (fewer live regs).

typedef __attribute__((ext_vector_type(8))) short short8;
typedef __attribute__((ext_vector_type(4))) float f32x4;

#define DEVINL __device__ __forceinline__

DEVINL float bf2f(ushort u) { union { uint32_t i; float f; } w; w.i = (uint32_t)u << 16; return w.f; }
DEVINL ushort f2bf(float f) {
  union { float f; uint32_t i; } w; w.f = f;
  uint32_t r = w.i + 0x7FFFu + ((w.i >> 16) & 1u);   // RNE
  return (ushort)(r >> 16);
}

DEVINL void gl_lds16(const ushort* g, ushort* l) {
  __builtin_amdgcn_global_load_lds(
      (const __attribute__((address_space(1))) uint32_t*)g,
      (__attribute__((address_space(3))) uint32_t*)l, 16, 0, 0);
}

// ---------------- fp32 -> bf16 convert (8 elems/thread), optional scale ----------------
__global__ __launch_bounds__(256) void cvt_f32_bf16(const float* __restrict__ in,
                                                    ushort* __restrict__ out,
                                                    int n8, float scale) {
  int i = blockIdx.x * 256 + threadIdx.x;
  if (i >= n8) return;
  const float4* p = (const float4*)in + (size_t)i * 2;
  float4 a = p[0], b = p[1];
  short8 o;
  o[0] = (short)f2bf(a.x * scale); o[1] = (short)f2bf(a.y * scale);
  o[2] = (short)f2bf(a.z * scale); o[3] = (short)f2bf(a.w * scale);
  o[4] = (short)f2bf(b.x * scale); o[5] = (short)f2bf(b.y * scale);
  o[6] = (short)f2bf(b.z * scale); o[7] = (short)f2bf(b.w * scale);
  ((short8*)out)[i] = o;
}

// ---------------- zero fp32 buffer ----------------
__global__ __launch_bounds__(256) void zerof4(float4* __restrict__ p, int n4) {
  int i = blockIdx.x * 256 + threadIdx.x;
  if (i < n4) p[i] = float4{0.f, 0.f, 0.f, 0.f};
}

// ================= 256x256 / BK=64 / 8-wave bf16 C = A * B^T (verified R7/R8) =================
template<bool CSKIP, bool CKB, int EPI, bool ZBH, bool SWZ>
__global__ __launch_bounds__(512, 2) void gemm256(
    const ushort* __restrict__ A0, long long sAb, long long sAh,
    const ushort* __restrict__ B0, long long sBb, long long sBh,
    void* __restrict__ C0, long long sCb, long long sCh,
    int lda, int ldb, int ldc, int K)
{
  int bm, bn;
  if (SWZ) {
    const int X = gridDim.x, nwg = X * gridDim.y;
    const int bid = blockIdx.y * X + blockIdx.x;
    const int cpx = nwg >> 3;
    const int swz = (bid & 7) * cpx + (bid >> 3);
    bm = swz % X; bn = swz / X;
  } else {
    bm = blockIdx.x; bn = blockIdx.y;
  }
  const int bz = blockIdx.z;
  if (CSKIP && bn > bm) return;
  long long za, zb, zc;
  if (ZBH) {
    const long long bi = bz >> 3, hi = bz & 7;
    za = bi * sAb + hi * sAh; zb = bi * sBb + hi * sBh; zc = bi * sCb + hi * sCh;
  } else {
    za = (long long)bz * sAh; zb = (long long)bz * sBh; zc = (long long)bz * sCh;
  }
  const ushort* A = A0 + za;
  const ushort* B = B0 + zb;
  int kend = K;
  if (CKB) { int kb = (bm + 1) * 256; kend = kb < K ? kb : K; }

  __shared__ ushort smem[65536];

  const int tid = threadIdx.x;
  const int wid = tid >> 6, lane = tid & 63;
  const int wr = wid >> 2, wc = wid & 3;
  const int l15 = lane & 15, kq = lane >> 4;

  const int srow8 = lane >> 3;
  const int schunk = ((lane & 7) ^ srow8) * 8;
  const ushort* ag = A + (size_t)(bm * 256 + wid * 8 + srow8) * lda + schunk;
  const ushort* bg = B + (size_t)(bn * 256 + wid * 8 + srow8) * ldb + schunk;

  auto STA = [&](int buf, int band, int kk) {
    gl_lds16(ag + (size_t)band * 64 * lda + kk, &smem[buf * 32768 + band * 4096 + wid * 512]);
  };
  auto STB = [&](int buf, int band, int kk) {
    gl_lds16(bg + (size_t)band * 64 * ldb + kk, &smem[buf * 32768 + 16384 + band * 4096 + wid * 512]);
  };
  auto STAGE8 = [&](int buf, int kk) {
    STB(buf, 0, kk); STB(buf, 1, kk); STB(buf, 2, kk); STB(buf, 3, kk);
    STA(buf, 0, kk); STA(buf, 2, kk); STA(buf, 1, kk); STA(buf, 3, kk);
  };

  f32x4 acc[8][4] = {};
  const int nt = kend >> 6;

  STAGE8(0, 0);

  for (int t = 0; t < nt; ++t) {
    const int cur = t & 1;
    const ushort* As = &smem[cur * 32768];
    const ushort* Bs = As + 16384;
    const bool pre = (t + 1 < nt);

    short8 bq[4], av[4];
    auto LDB = [&](int ks) {
#pragma unroll
      for (int n = 0; n < 4; ++n)
        bq[n] = *(const short8*)
            &Bs[(wc * 64 + n * 16 + l15) * 64 + (((ks * 4 + kq) ^ (l15 & 7)) * 8)];
    };
    auto LDA = [&](int mh, int ks) {
#pragma unroll
      for (int m = 0; m < 4; ++m)
        av[m] = *(const short8*)
            &As[(wr * 128 + mh * 64 + m * 16 + l15) * 64 + (((ks * 4 + kq) ^ (l15 & 7)) * 8)];
    };
    auto MFMAQ = [&](int mh) {
      __builtin_amdgcn_s_setprio(1);
#pragma unroll
      for (int m = 0; m < 4; ++m)
#pragma unroll
        for (int n = 0; n < 4; ++n)
          acc[mh * 4 + m][n] =
              __builtin_amdgcn_mfma_f32_16x16x32_bf16(av[m], bq[n], acc[mh * 4 + m][n], 0, 0, 0);
      __builtin_amdgcn_s_setprio(0);
    };

    if (pre) {
      STAGE8(cur ^ 1, (t + 1) << 6);
      asm volatile("s_waitcnt vmcnt(10)" ::: "memory");
    } else {
      asm volatile("s_waitcnt vmcnt(2)" ::: "memory");
    }
    __builtin_amdgcn_sched_barrier(0);
    __builtin_amdgcn_s_barrier();
    __builtin_amdgcn_sched_barrier(0);
    LDB(0); LDA(0, 0); MFMAQ(0);

    if (pre) asm volatile("s_waitcnt vmcnt(8)" ::: "memory");
    else     asm volatile("s_waitcnt vmcnt(0)" ::: "memory");
    __builtin_amdgcn_sched_barrier(0);
    __builtin_amdgcn_s_barrier();
    __builtin_amdgcn_sched_barrier(0);
    LDA(1, 0); MFMAQ(1);

    LDB(1); LDA(0, 1); MFMAQ(0);

    LDA(1, 1); MFMAQ(1);
    asm volatile("s_waitcnt lgkmcnt(0)" ::: "memory");
    __builtin_amdgcn_sched_barrier(0);
    __builtin_amdgcn_s_barrier();
    __builtin_amdgcn_sched_barrier(0);
  }

  if constexpr (EPI == 0) {
#pragma unroll
    for (int m = 0; m < 8; ++m)
#pragma unroll
      for (int n = 0; n < 4; ++n)
#pragma unroll
        for (int r = 0; r < 4; ++r) {
          const int row = wr * 128 + m * 16 + kq * 4 + r;
          const int col = wc * 64 + n * 16 + l15;
          smem[row * 256 + (((col >> 3) ^ (row & 31)) * 8) + (col & 7)] = f2bf(acc[m][n][r]);
        }
    __syncthreads();
    ushort* C = (ushort*)C0 + zc;
#pragma unroll
    for (int j = 0; j < 16; ++j) {
      const int chi = j * 512 + tid;
      const int row = chi >> 5, cc = chi & 31;
      *(short8*)&C[(size_t)(bm * 256 + row) * ldc + bn * 256 + cc * 8] =
          *(const short8*)&smem[row * 256 + ((cc ^ (row & 31)) * 8)];
    }
  } else {
    float* C = (float*)C0 + zc;
#pragma unroll
    for (int m = 0; m < 8; ++m)
#pragma unroll
      for (int n = 0; n < 4; ++n)
#pragma unroll
        for (int r = 0; r < 4; ++r)
          atomicAdd(&C[(size_t)(bm * 256 + wr * 128 + m * 16 + kq * 4 + r) * ldc
                       + bn * 256 + wc * 64 + n * 16 + l15], acc[m][n][r]);
  }
}

// ================= fused flash attention (group-local) =================
// Grid (8 q-blocks, 8g bh), 512 thr / 8 waves; wave owns 16 q-rows (QBLK=128).
// QKg: [g*1024][8192] rows = group tokens, cols 0..4095 Q | 4096..8191 K (head h at h*512).
// Vtg: [8g][512][1024]. Output AOg: [g*1024][4096].
// launch_bounds (512,2): same register regime as gemm256 (keeps 128-f32 acc in AGPRs,
// no scratch spill — R10's bare (512) allocated 128 VGPR and spilled accO).
__global__ __launch_bounds__(512, 2) void fused_attn(
    const ushort* __restrict__ QKg, const ushort* __restrict__ Vtg,
    ushort* __restrict__ AOg)
{
  const int qb = blockIdx.x;            // 0..7
  const int bh = blockIdx.y;            // 0..8g-1
  const int b = bh >> 3, h = bh & 7;    // group-local batch, head

  __shared__ ushort smem[69632];        // 2x(K 16384 | V 16384) + 8x512 P-scratch

  const int tid = threadIdx.x;
  const int wid = tid >> 6, lane = tid & 63;
  const int l15 = lane & 15, kq = lane >> 4;

  const ushort* Qb = QKg + (size_t)(b * 1024 + qb * 128 + wid * 16) * 8192 + h * 512;
  const ushort* Kb = QKg + (size_t)b * 1024 * 8192 + 4096 + h * 512;
  const ushort* Vb = Vtg + (size_t)bh * 524288;    // [512][1024]

  // Q fragments: lane l15 = row, cols kt*32 + kq*8
  short8 qf[16];
#pragma unroll
  for (int kt = 0; kt < 16; ++kt)
    qf[kt] = *(const short8*)&Qb[(size_t)l15 * 8192 + kt * 32 + kq * 8];

  // staging (rule #21): linear gl_lds dest + inverse-swizzled per-lane global source.
  // K rows r (1KB): LDS chunk p holds global chunk (p&56)|((p^r)&7).
  // V rows d (64B): LDS chunk c holds global chunk c^(d&3).
  auto STAGE = [&](int buf, int t) {
    const int s0 = t * 32;
#pragma unroll
    for (int q = 0; q < 4; ++q) {
      const int r = wid * 4 + q;
      const int sc = (lane & 56) | ((lane ^ r) & 7);
      gl_lds16(Kb + (size_t)(s0 + r) * 8192 + sc * 8, &smem[buf * 32768 + r * 512]);
    }
#pragma unroll
    for (int q = 0; q < 4; ++q) {
      const int dbase = wid * 64 + q * 16;
      const int d = dbase + (lane >> 2);
      const int sc = ((lane & 3) ^ ((lane >> 2) & 3)) * 8;
      gl_lds16(Vb + (size_t)d * 1024 + s0 + sc, &smem[buf * 32768 + 16384 + dbase * 32]);
    }
  };

  const int nkv = (qb + 1) * 4;
  const int qrow0 = qb * 128 + wid * 16 + kq * 4;   // + r
  float mrow[4] = {-3e38f, -3e38f, -3e38f, -3e38f};
  float lrow[4] = {0.f, 0.f, 0.f, 0.f};
  f32x4 accO[32] = {};
  ushort* PS = &smem[65536 + wid * 512];

  STAGE(0, 0);
  for (int t = 0; t < nkv; ++t) {
    const int cur = t & 1;
    if (t + 1 < nkv) {
      STAGE(cur ^ 1, t + 1);
      asm volatile("s_waitcnt vmcnt(8)" ::: "memory");
    } else {
      asm volatile("s_waitcnt vmcnt(0)" ::: "memory");
    }
    __builtin_amdgcn_sched_barrier(0);
    __builtin_amdgcn_s_barrier();
    __builtin_amdgcn_sched_barrier(0);

    const ushort* KL = &smem[cur * 32768];
    const ushort* VL = KL + 16384;
    const int s0 = t * 32;

    // ---- QK^T: S-tile 16q x 32s, Q from regs, K from LDS
    f32x4 sA = {0.f, 0.f, 0.f, 0.f}, sB = {0.f, 0.f, 0.f, 0.f};
    __builtin_amdgcn_s_setprio(1);
#pragma unroll
    for (int kt = 0; kt < 16; ++kt) {
      const int gc = kt * 4 + kq;
      const int pos = ((gc & 56) | ((gc ^ l15) & 7)) * 8;
      short8 k0 = *(const short8*)&KL[l15 * 512 + pos];
      short8 k1 = *(const short8*)&KL[(16 + l15) * 512 + pos];
      sA = __builtin_amdgcn_mfma_f32_16x16x32_bf16(qf[kt], k0, sA, 0, 0, 0);
      sB = __builtin_amdgcn_mfma_f32_16x16x32_bf16(qf[kt], k1, sB, 0, 0, 0);
    }
    __builtin_amdgcn_s_setprio(0);

    // ---- causal mask + online softmax, single path (sc==1 exactly when no max growth)
#pragma unroll
    for (int r = 0; r < 4; ++r) {
      float a = sA[r], c = sB[r];
      if (s0 + l15      > qrow0 + r) a = -3e38f;
      if (s0 + 16 + l15 > qrow0 + r) c = -3e38f;
      float mx = fmaxf(a, c);
      mx = fmaxf(mx, __shfl_xor(mx, 1));
      mx = fmaxf(mx, __shfl_xor(mx, 2));
      mx = fmaxf(mx, __shfl_xor(mx, 4));
      mx = fmaxf(mx, __shfl_xor(mx, 8));
      const float mn = fmaxf(mrow[r], mx);
      const float sc = __expf(mrow[r] - mn);
      mrow[r] = mn;
      const float e0 = __expf(a - mn);
      const float e1 = __expf(c - mn);
      float s = e0 + e1;
      s += __shfl_xor(s, 1); s += __shfl_xor(s, 2);
      s += __shfl_xor(s, 4); s += __shfl_xor(s, 8);
      lrow[r] = lrow[r] * sc + s;
#pragma unroll
      for (int j = 0; j < 32; ++j) accO[j][r] *= sc;

      // P row -> wave-private LDS transpose (XOR on q&3)
      const int q = kq * 4 + r;
      const int s1 = 16 + l15;
      PS[q * 32 + (((l15 >> 3) ^ (q & 3)) * 8) + (l15 & 7)] = f2bf(e0);
      PS[q * 32 + (((s1 >> 3) ^ (q & 3)) * 8) + (s1 & 7)]   = f2bf(e1);
    }
    short8 pa = *(const short8*)&PS[l15 * 32 + ((kq ^ (l15 & 3)) * 8)];

    // ---- PV: accO[j] (rows q, cols j*16+l15) += P · V
    __builtin_amdgcn_s_setprio(1);
#pragma unroll
    for (int j = 0; j < 32; ++j) {
      short8 bv = *(const short8*)&VL[(j * 16 + l15) * 32 + ((kq ^ (l15 & 3)) * 8)];
      accO[j] = __builtin_amdgcn_mfma_f32_16x16x32_bf16(pa, bv, accO[j], 0, 0, 0);
    }
    __builtin_amdgcn_s_setprio(0);

    asm volatile("s_waitcnt lgkmcnt(0)" ::: "memory");
    __builtin_amdgcn_sched_barrier(0);
    __builtin_amdgcn_s_barrier();                  // buf handoff; vmem prefetch survives
    __builtin_amdgcn_sched_barrier(0);
  }

  // ---- epilogue: O/l -> bf16, wave-private LDS stage (16x512 swizzled), coalesced stores
  ushort* OS = &smem[wid * 8192];
#pragma unroll
  for (int r = 0; r < 4; ++r) {
    const float iv = 1.f / lrow[r];
    const int q = kq * 4 + r;
#pragma unroll
    for (int j = 0; j < 32; ++j) {
      const int col = j * 16 + l15;
      const int ch = col >> 3;
      OS[q * 512 + (((ch & 56) | ((ch ^ q) & 7)) * 8) + (col & 7)] = f2bf(accO[j][r] * iv);
    }
  }
  ushort* AOb = AOg + (size_t)(b * 1024 + qb * 128 + wid * 16) * 4096 + h * 512;
#pragma unroll
  for (int it = 0; it < 16; ++it) {
    const int q = it, c = lane;
    const int pos = (c & 56) | ((c ^ q) & 7);
    *(short8*)&AOb[(size_t)q * 4096 + c * 8] = *(const short8*)&OS[q * 512 + pos * 8];
  }
}

// ---------------- V transpose: Vtmp[b*1024+s][h*512+d] -> Vt[bh][d][s] (group-local) -------
__global__ __launch_bounds__(256) void transposeV(const ushort* __restrict__ Vtmp,
                                                  ushort* __restrict__ Vt) {
  __shared__ ushort tile[64][72];
  const int bx = blockIdx.x;          // s-tile (16)
  const int by = blockIdx.y;          // d-tile (8)
  const int bz = blockIdx.z;          // bh (8g)
  const int b = bz >> 3, h = bz & 7;
  const int t = threadIdx.x;
  const int r = t >> 2, c = (t & 3) * 16;

  const ushort* src = Vtmp + (size_t)(b * 1024 + bx * 64 + r) * 4096 + h * 512 + by * 64 + c;
  short8 v0 = *(const short8*)src;
  short8 v1 = *(const short8*)(src + 8);
#pragma unroll
  for (int j = 0; j < 8; ++j) { tile[r][c + j] = (ushort)v0[j]; tile[r][c + 8 + j] = (ushort)v1[j]; }
  __syncthreads();

  ushort* dst = Vt + (size_t)(bz * 512 + by * 64 + r) * 1024 + bx * 64 + c;
  short8 o0, o1;
#pragma unroll
  for (int j = 0; j < 8; ++j) { o0[j] = (short)tile[c + j][r]; o1[j] = (short)tile[c + 8 + j][r]; }
  *(short8*)dst = o0;
  *(short8*)(dst + 8) = o1;
}

// ---------------- launch ----------------
extern "C" void kernel_launch(void* const* d_in, const int* in_sizes, int n_in,
                              void* d_out, int out_size, void* d_ws, size_t ws_size,
                              hipStream_t stream) {
  const float* x  = (const float*)d_in[0];
  const float* Wq = (const float*)d_in[1];
  const float* Wk = (const float*)d_in[2];
  const float* Wv = (const float*)d_in[3];
  const float* Wo = (const float*)d_in[4];
  float* out = (float*)d_out;

  // group size: R(g) = 92,274,688 + g*25,165,824 bytes; g=2 == proven 142,606,336 floor.
  const int g = (ws_size >= 293601280ull) ? 8 : (ws_size >= 192937984ull) ? 4 : 2;
  const int ng = 8 / g;

  // workspace layout (ushort elements)
  ushort* xb   = (ushort*)d_ws;                 //  8192*512     = 4,194,304
  ushort* Wqkv = xb   + (size_t)4194304;        // 12288*512     = 6,291,456
  ushort* Wob  = Wqkv + (size_t)6291456;        //   512*4096    = 2,097,152
  ushort* AO   = Wob  + (size_t)2097152;        //  8192*4096    = 33,554,432
  ushort* QKg  = AO   + (size_t)33554432;       //  g*1024*8192  = g*8,388,608
  ushort* Vtg  = QKg  + (size_t)g * 8388608;    //  g*8*512*1024 = g*4,194,304

  const float iscale = (float)(1.0 / pow(512.0, 0.25));   // folded into Wq, Wk

  cvt_f32_bf16<<<2048, 256, 0, stream>>>(x,  xb,             524288, 1.0f);
  cvt_f32_bf16<<<1024, 256, 0, stream>>>(Wq, Wqkv,           262144, iscale);
  cvt_f32_bf16<<<1024, 256, 0, stream>>>(Wk, Wqkv + 2097152, 262144, iscale);
  cvt_f32_bf16<<<1024, 256, 0, stream>>>(Wv, Wqkv + 4194304, 262144, 1.0f);
  cvt_f32_bf16<<<1024, 256, 0, stream>>>(Wo, Wob,            262144, 1.0f);

  for (int grp = 0; grp < ng; ++grp) {
    const ushort* xg = xb + (size_t)grp * g * 524288;
    ushort* AOg = AO + (size_t)grp * g * 4194304;

    // QKg = x[grp] @ (Wq|Wk)^T : [g*1024 x 8192]
    gemm256<false, false, 0, false, true><<<dim3(g * 4, 32, 1), 512, 0, stream>>>(
        xg, 0, 0, Wqkv, 0, 0, QKg, 0, 0, 512, 512, 8192, 512);

    // V-tmp = x[grp] @ Wv^T : [g*1024 x 4096] -> AOg region
    gemm256<false, false, 0, false, true><<<dim3(g * 4, 16, 1), 512, 0, stream>>>(
        xg, 0, 0, Wqkv + 4194304, 0, 0, AOg, 0, 0, 512, 512, 4096, 512);

    // V transpose -> Vtg[bh][d][s]
    transposeV<<<dim3(16, 8, 8 * g), 256, 0, stream>>>(AOg, Vtg);

    // fused flash attention -> AOg (overwrites V-tmp, already consumed)
    fused_attn<<<dim3(8, 8 * g), 512, 0, stream>>>(QKg, Vtg, AOg);
  }

  // out = AO @ Wo^T, fp32, K split x4 with atomic accumulate
  zerof4<<<4096, 256, 0, stream>>>((float4*)out, 1048576);
  gemm256<false, false, 2, false, true><<<dim3(32, 2, 4), 512, 0, stream>>>(
      AO,  0, 1024LL,
      Wob, 0, 1024LL,
      out, 0, 0LL,
      4096, 4096, 512, 1024);
}

// Round 13
// 590.052 us; speedup vs baseline: 2.6990x; 1.0359x over previous
//
#include <hip/hip_runtime.h>
#include <hip/hip_bf16.h>
#include <cstdint>
#include <cmath>

// Self-attention, B=8 T=1024 H=8 D=512 (hidden 4096), fp32 in/out, bf16 MFMA compute.
// Flash-fused attention (S never in memory), group-adaptive g in {8,4,2}.
// R12 (resubmitted after infra flake): (1) XCD-aware block remap in fused_attn — same-bh
// q-blocks land on one XCD so K/V stream from L2 (was 8x redundant HBM streaming);
// (2) V LDS swizzle XORs (d>>1)&3 — kills the 4-way PV read conflict (10.2M/dispatch);
// (3) accO rescale guarded by __any(max-grew) — exact skip, saves ~800 cy/tile.

typedef __attribute__((ext_vector_type(8))) short short8;
typedef __attribute__((ext_vector_type(4))) float f32x4;

#define DEVINL __device__ __forceinline__

DEVINL float bf2f(ushort u) { union { uint32_t i; float f; } w; w.i = (uint32_t)u << 16; return w.f; }
DEVINL ushort f2bf(float f) {
  union { float f; uint32_t i; } w; w.f = f;
  uint32_t r = w.i + 0x7FFFu + ((w.i >> 16) & 1u);   // RNE
  return (ushort)(r >> 16);
}

DEVINL void gl_lds16(const ushort* g, ushort* l) {
  __builtin_amdgcn_global_load_lds(
      (const __attribute__((address_space(1))) uint32_t*)g,
      (__attribute__((address_space(3))) uint32_t*)l, 16, 0, 0);
}

// ---------------- fp32 -> bf16 convert (8 elems/thread), optional scale ----------------
__global__ __launch_bounds__(256) void cvt_f32_bf16(const float* __restrict__ in,
                                                    ushort* __restrict__ out,
                                                    int n8, float scale) {
  int i = blockIdx.x * 256 + threadIdx.x;
  if (i >= n8) return;
  const float4* p = (const float4*)in + (size_t)i * 2;
  float4 a = p[0], b = p[1];
  short8 o;
  o[0] = (short)f2bf(a.x * scale); o[1] = (short)f2bf(a.y * scale);
  o[2] = (short)f2bf(a.z * scale); o[3] = (short)f2bf(a.w * scale);
  o[4] = (short)f2bf(b.x * scale); o[5] = (short)f2bf(b.y * scale);
  o[6] = (short)f2bf(b.z * scale); o[7] = (short)f2bf(b.w * scale);
  ((short8*)out)[i] = o;
}

// ---------------- zero fp32 buffer ----------------
__global__ __launch_bounds__(256) void zerof4(float4* __restrict__ p, int n4) {
  int i = blockIdx.x * 256 + threadIdx.x;
  if (i < n4) p[i] = float4{0.f, 0.f, 0.f, 0.f};
}

// ================= 256x256 / BK=64 / 8-wave bf16 C = A * B^T (verified R7/R8) =================
template<bool CSKIP, bool CKB, int EPI, bool ZBH, bool SWZ>
__global__ __launch_bounds__(512, 2) void gemm256(
    const ushort* __restrict__ A0, long long sAb, long long sAh,
    const ushort* __restrict__ B0, long long sBb, long long sBh,
    void* __restrict__ C0, long long sCb, long long sCh,
    int lda, int ldb, int ldc, int K)
{
  int bm, bn;
  if (SWZ) {
    const int X = gridDim.x, nwg = X * gridDim.y;
    const int bid = blockIdx.y * X + blockIdx.x;
    const int cpx = nwg >> 3;
    const int swz = (bid & 7) * cpx + (bid >> 3);
    bm = swz % X; bn = swz / X;
  } else {
    bm = blockIdx.x; bn = blockIdx.y;
  }
  const int bz = blockIdx.z;
  if (CSKIP && bn > bm) return;
  long long za, zb, zc;
  if (ZBH) {
    const long long bi = bz >> 3, hi = bz & 7;
    za = bi * sAb + hi * sAh; zb = bi * sBb + hi * sBh; zc = bi * sCb + hi * sCh;
  } else {
    za = (long long)bz * sAh; zb = (long long)bz * sBh; zc = (long long)bz * sCh;
  }
  const ushort* A = A0 + za;
  const ushort* B = B0 + zb;
  int kend = K;
  if (CKB) { int kb = (bm + 1) * 256; kend = kb < K ? kb : K; }

  __shared__ ushort smem[65536];

  const int tid = threadIdx.x;
  const int wid = tid >> 6, lane = tid & 63;
  const int wr = wid >> 2, wc = wid & 3;
  const int l15 = lane & 15, kq = lane >> 4;

  const int srow8 = lane >> 3;
  const int schunk = ((lane & 7) ^ srow8) * 8;
  const ushort* ag = A + (size_t)(bm * 256 + wid * 8 + srow8) * lda + schunk;
  const ushort* bg = B + (size_t)(bn * 256 + wid * 8 + srow8) * ldb + schunk;

  auto STA = [&](int buf, int band, int kk) {
    gl_lds16(ag + (size_t)band * 64 * lda + kk, &smem[buf * 32768 + band * 4096 + wid * 512]);
  };
  auto STB = [&](int buf, int band, int kk) {
    gl_lds16(bg + (size_t)band * 64 * ldb + kk, &smem[buf * 32768 + 16384 + band * 4096 + wid * 512]);
  };
  auto STAGE8 = [&](int buf, int kk) {
    STB(buf, 0, kk); STB(buf, 1, kk); STB(buf, 2, kk); STB(buf, 3, kk);
    STA(buf, 0, kk); STA(buf, 2, kk); STA(buf, 1, kk); STA(buf, 3, kk);
  };

  f32x4 acc[8][4] = {};
  const int nt = kend >> 6;

  STAGE8(0, 0);

  for (int t = 0; t < nt; ++t) {
    const int cur = t & 1;
    const ushort* As = &smem[cur * 32768];
    const ushort* Bs = As + 16384;
    const bool pre = (t + 1 < nt);

    short8 bq[4], av[4];
    auto LDB = [&](int ks) {
#pragma unroll
      for (int n = 0; n < 4; ++n)
        bq[n] = *(const short8*)
            &Bs[(wc * 64 + n * 16 + l15) * 64 + (((ks * 4 + kq) ^ (l15 & 7)) * 8)];
    };
    auto LDA = [&](int mh, int ks) {
#pragma unroll
      for (int m = 0; m < 4; ++m)
        av[m] = *(const short8*)
            &As[(wr * 128 + mh * 64 + m * 16 + l15) * 64 + (((ks * 4 + kq) ^ (l15 & 7)) * 8)];
    };
    auto MFMAQ = [&](int mh) {
      __builtin_amdgcn_s_setprio(1);
#pragma unroll
      for (int m = 0; m < 4; ++m)
#pragma unroll
        for (int n = 0; n < 4; ++n)
          acc[mh * 4 + m][n] =
              __builtin_amdgcn_mfma_f32_16x16x32_bf16(av[m], bq[n], acc[mh * 4 + m][n], 0, 0, 0);
      __builtin_amdgcn_s_setprio(0);
    };

    if (pre) {
      STAGE8(cur ^ 1, (t + 1) << 6);
      asm volatile("s_waitcnt vmcnt(10)" ::: "memory");
    } else {
      asm volatile("s_waitcnt vmcnt(2)" ::: "memory");
    }
    __builtin_amdgcn_sched_barrier(0);
    __builtin_amdgcn_s_barrier();
    __builtin_amdgcn_sched_barrier(0);
    LDB(0); LDA(0, 0); MFMAQ(0);

    if (pre) asm volatile("s_waitcnt vmcnt(8)" ::: "memory");
    else     asm volatile("s_waitcnt vmcnt(0)" ::: "memory");
    __builtin_amdgcn_sched_barrier(0);
    __builtin_amdgcn_s_barrier();
    __builtin_amdgcn_sched_barrier(0);
    LDA(1, 0); MFMAQ(1);

    LDB(1); LDA(0, 1); MFMAQ(0);

    LDA(1, 1); MFMAQ(1);
    asm volatile("s_waitcnt lgkmcnt(0)" ::: "memory");
    __builtin_amdgcn_sched_barrier(0);
    __builtin_amdgcn_s_barrier();
    __builtin_amdgcn_sched_barrier(0);
  }

  if constexpr (EPI == 0) {
#pragma unroll
    for (int m = 0; m < 8; ++m)
#pragma unroll
      for (int n = 0; n < 4; ++n)
#pragma unroll
        for (int r = 0; r < 4; ++r) {
          const int row = wr * 128 + m * 16 + kq * 4 + r;
          const int col = wc * 64 + n * 16 + l15;
          smem[row * 256 + (((col >> 3) ^ (row & 31)) * 8) + (col & 7)] = f2bf(acc[m][n][r]);
        }
    __syncthreads();
    ushort* C = (ushort*)C0 + zc;
#pragma unroll
    for (int j = 0; j < 16; ++j) {
      const int chi = j * 512 + tid;
      const int row = chi >> 5, cc = chi & 31;
      *(short8*)&C[(size_t)(bm * 256 + row) * ldc + bn * 256 + cc * 8] =
          *(const short8*)&smem[row * 256 + ((cc ^ (row & 31)) * 8)];
    }
  } else {
    float* C = (float*)C0 + zc;
#pragma unroll
    for (int m = 0; m < 8; ++m)
#pragma unroll
      for (int n = 0; n < 4; ++n)
#pragma unroll
        for (int r = 0; r < 4; ++r)
          atomicAdd(&C[(size_t)(bm * 256 + wr * 128 + m * 16 + kq * 4 + r) * ldc
                       + bn * 256 + wc * 64 + n * 16 + l15], acc[m][n][r]);
  }
}

// ================= fused flash attention (group-local, XCD-swizzled) =================
// Grid (8, 8g). Remap: lin = y*8+x; bh = lin%(8g); qb = lin/(8g) -> same-bh q-blocks
// have IDs spaced 8g (== 0 mod 8) -> same XCD -> K/V stream from that XCD's L2.
__global__ __launch_bounds__(512, 2) void fused_attn(
    const ushort* __restrict__ QKg, const ushort* __restrict__ Vtg,
    ushort* __restrict__ AOg)
{
  const int nbh = gridDim.y;                       // 8g
  const int lin = blockIdx.y * 8 + blockIdx.x;
  const int bh = lin % nbh;                        // group-local (batch,head)
  const int qb = lin / nbh;                        // 0..7
  const int b = bh >> 3, h = bh & 7;

  __shared__ ushort smem[69632];        // 2x(K 16384 | V 16384) + 8x512 P-scratch

  const int tid = threadIdx.x;
  const int wid = tid >> 6, lane = tid & 63;
  const int l15 = lane & 15, kq = lane >> 4;

  const ushort* Qb = QKg + (size_t)(b * 1024 + qb * 128 + wid * 16) * 8192 + h * 512;
  const ushort* Kb = QKg + (size_t)b * 1024 * 8192 + 4096 + h * 512;
  const ushort* Vb = Vtg + (size_t)bh * 524288;    // [512][1024]

  // Q fragments: lane l15 = row, cols kt*32 + kq*8
  short8 qf[16];
#pragma unroll
  for (int kt = 0; kt < 16; ++kt)
    qf[kt] = *(const short8*)&Qb[(size_t)l15 * 8192 + kt * 32 + kq * 8];

  // staging (rule #21): linear gl_lds dest + inverse-swizzled per-lane global source.
  // K rows r (1KB): LDS chunk p holds global chunk (p&56)|((p^r)&7).
  // V rows d (64B): LDS chunk c holds global chunk c^((d>>1)&3)  [depth-2 XOR].
  auto STAGE = [&](int buf, int t) {
    const int s0 = t * 32;
#pragma unroll
    for (int q = 0; q < 4; ++q) {
      const int r = wid * 4 + q;
      const int sc = (lane & 56) | ((lane ^ r) & 7);
      gl_lds16(Kb + (size_t)(s0 + r) * 8192 + sc * 8, &smem[buf * 32768 + r * 512]);
    }
#pragma unroll
    for (int q = 0; q < 4; ++q) {
      const int dbase = wid * 64 + q * 16;
      const int d = dbase + (lane >> 2);
      const int sc = ((lane & 3) ^ ((lane >> 3) & 3)) * 8;   // (d>>1)&3 == (lane>>3)&3
      gl_lds16(Vb + (size_t)d * 1024 + s0 + sc, &smem[buf * 32768 + 16384 + dbase * 32]);
    }
  };

  const int nkv = (qb + 1) * 4;
  const int qrow0 = qb * 128 + wid * 16 + kq * 4;   // + r
  float mrow[4] = {-3e38f, -3e38f, -3e38f, -3e38f};
  float lrow[4] = {0.f, 0.f, 0.f, 0.f};
  f32x4 accO[32] = {};
  ushort* PS = &smem[65536 + wid * 512];

  STAGE(0, 0);
  for (int t = 0; t < nkv; ++t) {
    const int cur = t & 1;
    if (t + 1 < nkv) {
      STAGE(cur ^ 1, t + 1);
      asm volatile("s_waitcnt vmcnt(8)" ::: "memory");
    } else {
      asm volatile("s_waitcnt vmcnt(0)" ::: "memory");
    }
    __builtin_amdgcn_sched_barrier(0);
    __builtin_amdgcn_s_barrier();
    __builtin_amdgcn_sched_barrier(0);

    const ushort* KL = &smem[cur * 32768];
    const ushort* VL = KL + 16384;
    const int s0 = t * 32;

    // ---- QK^T: S-tile 16q x 32s, Q from regs, K from LDS
    f32x4 sA = {0.f, 0.f, 0.f, 0.f}, sB = {0.f, 0.f, 0.f, 0.f};
    __builtin_amdgcn_s_setprio(1);
#pragma unroll
    for (int kt = 0; kt < 16; ++kt) {
      const int gc = kt * 4 + kq;
      const int pos = ((gc & 56) | ((gc ^ l15) & 7)) * 8;
      short8 k0 = *(const short8*)&KL[l15 * 512 + pos];
      short8 k1 = *(const short8*)&KL[(16 + l15) * 512 + pos];
      sA = __builtin_amdgcn_mfma_f32_16x16x32_bf16(qf[kt], k0, sA, 0, 0, 0);
      sB = __builtin_amdgcn_mfma_f32_16x16x32_bf16(qf[kt], k1, sB, 0, 0, 0);
    }
    __builtin_amdgcn_s_setprio(0);

    // ---- causal mask + online softmax, single exp path; guarded accO rescale
    float e0v[4], e1v[4], scv[4];
    int grew = 0;
#pragma unroll
    for (int r = 0; r < 4; ++r) {
      float a = sA[r], c = sB[r];
      if (s0 + l15      > qrow0 + r) a = -3e38f;
      if (s0 + 16 + l15 > qrow0 + r) c = -3e38f;
      float mx = fmaxf(a, c);
      mx = fmaxf(mx, __shfl_xor(mx, 1));
      mx = fmaxf(mx, __shfl_xor(mx, 2));
      mx = fmaxf(mx, __shfl_xor(mx, 4));
      mx = fmaxf(mx, __shfl_xor(mx, 8));
      grew |= (mx > mrow[r]);
      const float mn = fmaxf(mrow[r], mx);
      scv[r] = __expf(mrow[r] - mn);               // == 1.0 exactly when no growth
      mrow[r] = mn;
      const float e0 = __expf(a - mn);
      const float e1 = __expf(c - mn);
      float s = e0 + e1;
      s += __shfl_xor(s, 1); s += __shfl_xor(s, 2);
      s += __shfl_xor(s, 4); s += __shfl_xor(s, 8);
      lrow[r] = lrow[r] * scv[r] + s;
      e0v[r] = e0; e1v[r] = e1;
    }
    if (__any(grew)) {                             // skip exact when all sc == 1
#pragma unroll
      for (int r = 0; r < 4; ++r)
#pragma unroll
        for (int j = 0; j < 32; ++j) accO[j][r] *= scv[r];
    }

    // ---- P (16x32) -> bf16 A-frag via wave-private LDS transpose (XOR on q&3)
#pragma unroll
    for (int r = 0; r < 4; ++r) {
      const int q = kq * 4 + r;
      const int s1 = 16 + l15;
      PS[q * 32 + (((l15 >> 3) ^ (q & 3)) * 8) + (l15 & 7)] = f2bf(e0v[r]);
      PS[q * 32 + (((s1 >> 3) ^ (q & 3)) * 8) + (s1 & 7)]   = f2bf(e1v[r]);
    }
    short8 pa = *(const short8*)&PS[l15 * 32 + ((kq ^ (l15 & 3)) * 8)];

    // ---- PV: accO[j] (rows q, cols j*16+l15) += P · V   [V read: depth-2 XOR]
    __builtin_amdgcn_s_setprio(1);
#pragma unroll
    for (int j = 0; j < 32; ++j) {
      short8 bv = *(const short8*)&VL[(j * 16 + l15) * 32 + ((kq ^ ((l15 >> 1) & 3)) * 8)];
      accO[j] = __builtin_amdgcn_mfma_f32_16x16x32_bf16(pa, bv, accO[j], 0, 0, 0);
    }
    __builtin_amdgcn_s_setprio(0);

    asm volatile("s_waitcnt lgkmcnt(0)" ::: "memory");
    __builtin_amdgcn_sched_barrier(0);
    __builtin_amdgcn_s_barrier();                  // buf handoff; vmem prefetch survives
    __builtin_amdgcn_sched_barrier(0);
  }

  // ---- epilogue: O/l -> bf16, wave-private LDS stage (16x512 swizzled), coalesced stores
  ushort* OS = &smem[wid * 8192];
#pragma unroll
  for (int r = 0; r < 4; ++r) {
    const float iv = 1.f / lrow[r];
    const int q = kq * 4 + r;
#pragma unroll
    for (int j = 0; j < 32; ++j) {
      const int col = j * 16 + l15;
      const int ch = col >> 3;
      OS[q * 512 + (((ch & 56) | ((ch ^ q) & 7)) * 8) + (col & 7)] = f2bf(accO[j][r] * iv);
    }
  }
  ushort* AOb = AOg + (size_t)(b * 1024 + qb * 128 + wid * 16) * 4096 + h * 512;
#pragma unroll
  for (int it = 0; it < 16; ++it) {
    const int q = it, c = lane;
    const int pos = (c & 56) | ((c ^ q) & 7);
    *(short8*)&AOb[(size_t)q * 4096 + c * 8] = *(const short8*)&OS[q * 512 + pos * 8];
  }
}

// ---------------- V transpose: Vtmp[b*1024+s][h*512+d] -> Vt[bh][d][s] (group-local) -------
__global__ __launch_bounds__(256) void transposeV(const ushort* __restrict__ Vtmp,
                                                  ushort* __restrict__ Vt) {
  __shared__ ushort tile[64][72];
  const int bx = blockIdx.x;          // s-tile (16)
  const int by = blockIdx.y;          // d-tile (8)
  const int bz = blockIdx.z;          // bh (8g)
  const int b = bz >> 3, h = bz & 7;
  const int t = threadIdx.x;
  const int r = t >> 2, c = (t & 3) * 16;

  const ushort* src = Vtmp + (size_t)(b * 1024 + bx * 64 + r) * 4096 + h * 512 + by * 64 + c;
  short8 v0 = *(const short8*)src;
  short8 v1 = *(const short8*)(src + 8);
#pragma unroll
  for (int j = 0; j < 8; ++j) { tile[r][c + j] = (ushort)v0[j]; tile[r][c + 8 + j] = (ushort)v1[j]; }
  __syncthreads();

  ushort* dst = Vt + (size_t)(bz * 512 + by * 64 + r) * 1024 + bx * 64 + c;
  short8 o0, o1;
#pragma unroll
  for (int j = 0; j < 8; ++j) { o0[j] = (short)tile[c + j][r]; o1[j] = (short)tile[c + 8 + j][r]; }
  *(short8*)dst = o0;
  *(short8*)(dst + 8) = o1;
}

// ---------------- launch ----------------
extern "C" void kernel_launch(void* const* d_in, const int* in_sizes, int n_in,
                              void* d_out, int out_size, void* d_ws, size_t ws_size,
                              hipStream_t stream) {
  const float* x  = (const float*)d_in[0];
  const float* Wq = (const float*)d_in[1];
  const float* Wk = (const float*)d_in[2];
  const float* Wv = (const float*)d_in[3];
  const float* Wo = (const float*)d_in[4];
  float* out = (float*)d_out;

  // group size: R(g) = 92,274,688 + g*25,165,824 bytes (R11 proved ws_size >= R(4)).
  const int g = (ws_size >= 293601280ull) ? 8 : (ws_size >= 192937984ull) ? 4 : 2;
  const int ng = 8 / g;

  // workspace layout (ushort elements)
  ushort* xb   = (ushort*)d_ws;                 //  8192*512     = 4,194,304
  ushort* Wqkv = xb   + (size_t)4194304;        // 12288*512     = 6,291,456
  ushort* Wob  = Wqkv + (size_t)6291456;        //   512*4096    = 2,097,152
  ushort* AO   = Wob  + (size_t)2097152;        //  8192*4096    = 33,554,432
  ushort* QKg  = AO   + (size_t)33554432;       //  g*1024*8192  = g*8,388,608
  ushort* Vtg  = QKg  + (size_t)g * 8388608;    //  g*8*512*1024 = g*4,194,304

  const float iscale = (float)(1.0 / pow(512.0, 0.25));   // folded into Wq, Wk

  cvt_f32_bf16<<<2048, 256, 0, stream>>>(x,  xb,             524288, 1.0f);
  cvt_f32_bf16<<<1024, 256, 0, stream>>>(Wq, Wqkv,           262144, iscale);
  cvt_f32_bf16<<<1024, 256, 0, stream>>>(Wk, Wqkv + 2097152, 262144, iscale);
  cvt_f32_bf16<<<1024, 256, 0, stream>>>(Wv, Wqkv + 4194304, 262144, 1.0f);
  cvt_f32_bf16<<<1024, 256, 0, stream>>>(Wo, Wob,            262144, 1.0f);

  for (int grp = 0; grp < ng; ++grp) {
    const ushort* xg = xb + (size_t)grp * g * 524288;
    ushort* AOg = AO + (size_t)grp * g * 4194304;

    // QKg = x[grp] @ (Wq|Wk)^T : [g*1024 x 8192]
    gemm256<false, false, 0, false, true><<<dim3(g * 4, 32, 1), 512, 0, stream>>>(
        xg, 0, 0, Wqkv, 0, 0, QKg, 0, 0, 512, 512, 8192, 512);

    // V-tmp = x[grp] @ Wv^T : [g*1024 x 4096] -> AOg region
    gemm256<false, false, 0, false, true><<<dim3(g * 4, 16, 1), 512, 0, stream>>>(
        xg, 0, 0, Wqkv + 4194304, 0, 0, AOg, 0, 0, 512, 512, 4096, 512);

    // V transpose -> Vtg[bh][d][s]
    transposeV<<<dim3(16, 8, 8 * g), 256, 0, stream>>>(AOg, Vtg);

    // fused flash attention -> AOg (overwrites V-tmp, already consumed)
    fused_attn<<<dim3(8, 8 * g), 512, 0, stream>>>(QKg, Vtg, AOg);
  }

  // out = AO @ Wo^T, fp32, K split x4 with atomic accumulate
  zerof4<<<4096, 256, 0, stream>>>((float4*)out, 1048576);
  gemm256<false, false, 2, false, true><<<dim3(32, 2, 4), 512, 0, stream>>>(
      AO,  0, 1024LL,
      Wob, 0, 1024LL,
      out, 0, 0LL,
      4096, 4096, 512, 1024);
}